// Round 2
// baseline (230.197 us; speedup 1.0000x reference)
//
#include <hip/hip_runtime.h>

#define N_CAND 462080   // 16*76*76*5
#define NBINS  8192
#define TARGET 1024u
#define SMAX   2048
#define SCORE_THR 0.02f

// ---------------- ws layout (bytes) ----------------
// ctrl   : 2 x u32    @ 0        ([0]=compact count, [1]=cutoff bin)
// hist   : 8192 x u32 @ 256
// lscore : 2048 x f32 @ 33280
// lidx   : 2048 x i32 @ 41472
// scores : N x f32    @ 65536
// cls    : N x i32    @ 65536 + N*4
// total ~ 3.8 MB

// ============ Kernel 1: decode (HBM-bound, LDS-staged) ============
__global__ __launch_bounds__(128) void decode_kernel(
    const float* __restrict__ feats,
    float* __restrict__ scores, int* __restrict__ cls,
    unsigned int* __restrict__ hist)
{
    __shared__ __align__(16) float lds[128 * 85];   // 43520 B
    const int t = threadIdx.x;
    const long long base = (long long)blockIdx.x * 128;

    // coalesced staging: 128*85 floats = 2720 float4, base is 16B-aligned
    const float4* __restrict__ src = (const float4*)(feats + base * 85);
    float4* dst = (float4*)lds;
#pragma unroll
    for (int i = 0; i < 22; ++i) {
        int p = t + i * 128;
        if (p < 2720) dst[p] = src[p];
    }
    __syncthreads();

    const float* f = lds + t * 85;   // stride 85 (odd) -> conflict-free
    const int ci = (int)base + t;

    // class argmax over raw logits (== argmax of softmax, first-index ties)
    float m = f[5];
    int cbest = 0;
#pragma unroll
    for (int k = 1; k < 80; ++k) {
        float v = f[5 + k];
        if (v > m) { m = v; cbest = k; }
    }
    // softmax max-prob = 1 / sum(exp(l - m))
    float s0 = 0.f, s1 = 0.f, s2 = 0.f, s3 = 0.f;
#pragma unroll
    for (int k = 0; k < 80; k += 4) {
        s0 += __expf(f[5 + k] - m);
        s1 += __expf(f[6 + k] - m);
        s2 += __expf(f[7 + k] - m);
        s3 += __expf(f[8 + k] - m);
    }
    float ssum = (s0 + s1) + (s2 + s3);
    float conf = 1.0f / (1.0f + __expf(-f[4]));
    float score = conf * (1.0f / ssum);

    cls[ci] = cbest;
    float sw = (score >= SCORE_THR) ? score : -1.0f;
    scores[ci] = sw;
    if (score >= SCORE_THR) {
        int bin = (int)(score * (float)NBINS);
        bin = bin > (NBINS - 1) ? (NBINS - 1) : bin;
        atomicAdd(&hist[bin], 1u);
    }
}

// ============ Kernel 2: find cutoff bin (1 block) ============
__global__ __launch_bounds__(1024) void cutoff_kernel(
    const unsigned int* __restrict__ hist, unsigned int* __restrict__ ctrl)
{
    __shared__ unsigned int lh[NBINS];
    __shared__ unsigned int psum[1024];
    const int t = threadIdx.x;
    unsigned s = 0;
#pragma unroll
    for (int i = 0; i < 8; ++i) {
        unsigned v = hist[t * 8 + i];
        lh[t * 8 + i] = v;
        s += v;
    }
    psum[t] = s;
    __syncthreads();
    // inclusive suffix scan (Hillis-Steele)
    for (int off = 1; off < 1024; off <<= 1) {
        unsigned add = (t + off < 1024) ? psum[t + off] : 0u;
        __syncthreads();
        psum[t] += add;
        __syncthreads();
    }
    unsigned St = psum[t];
    unsigned Sn = (t < 1023) ? psum[t + 1] : 0u;
    // unique crossing thread finds b* = max{b : suffix(b) >= TARGET}
    if (St >= TARGET && Sn < TARGET) {
        unsigned run = Sn;
#pragma unroll
        for (int i = 7; i >= 0; --i) {
            run += lh[t * 8 + i];
            if (run >= TARGET) { ctrl[1] = (unsigned)(t * 8 + i); break; }
        }
    }
    // if total < TARGET, ctrl[1] stays 0 (memset) -> select all valid
}

// ============ Kernel 3: compact candidates >= cutoff ============
__global__ __launch_bounds__(256) void compact_kernel(
    const float* __restrict__ scores, unsigned int* __restrict__ ctrl,
    float* __restrict__ lscore, int* __restrict__ lidx)
{
    int i = blockIdx.x * 256 + threadIdx.x;
    float sw = scores[i];
    if (sw >= SCORE_THR) {
        int bin = (int)(sw * (float)NBINS);
        bin = bin > (NBINS - 1) ? (NBINS - 1) : bin;
        if (bin >= (int)ctrl[1]) {
            unsigned pos = atomicAdd(&ctrl[0], 1u);
            if (pos < SMAX) { lscore[pos] = sw; lidx[pos] = i; }
        }
    }
}

// box decode for one candidate (matches reference formulas, fp32)
__device__ inline float4 decode_box(const float* __restrict__ feats,
                                    const float* __restrict__ anchors, int ci)
{
    int a = ci % 5;
    int cell = ci / 5;
    int gx = cell % 76;
    int gy = (cell / 76) % 76;
    const float* f = feats + (long long)ci * 85;
    float bx = (1.0f / (1.0f + __expf(-f[0])) + (float)gx) / 76.0f;
    float by = (1.0f / (1.0f + __expf(-f[1])) + (float)gy) / 76.0f;
    float bw = __expf(f[2]) * anchors[2 * a]     / 76.0f;
    float bh = __expf(f[3]) * anchors[2 * a + 1] / 76.0f;
    return make_float4(by - bh * 0.5f, bx - bw * 0.5f,
                       by + bh * 0.5f, bx + bw * 0.5f);  // y1,x1,y2,x2
}

// ============ Kernel 4: sort + greedy NMS (1 block) ============
__global__ __launch_bounds__(1024) void nms_kernel(
    const float* __restrict__ lscore, const int* __restrict__ lidx,
    const unsigned int* __restrict__ ctrl,
    const float* __restrict__ feats, const float* __restrict__ anchors,
    const int* __restrict__ cls, float* __restrict__ out)
{
    __shared__ float  ss[SMAX];
    __shared__ int    si[SMAX];
    __shared__ float4 sb[SMAX];
    __shared__ unsigned char alive[SMAX];
    __shared__ int red[1024];
    const int t = threadIdx.x;

    unsigned cnt = ctrl[0];
    int n = (cnt < (unsigned)SMAX) ? (int)cnt : SMAX;

#pragma unroll
    for (int v = 0; v < 2; ++v) {
        int p = t + v * 1024;
        if (p < n) { ss[p] = lscore[p]; si[p] = lidx[p]; }
        else       { ss[p] = -2.0f;     si[p] = 0x7fffffff; }
    }
    __syncthreads();

    // bitonic sort, rank = (score desc, idx asc)
    for (int k = 2; k <= SMAX; k <<= 1) {
        for (int j = k >> 1; j > 0; j >>= 1) {
#pragma unroll
            for (int v = 0; v < 2; ++v) {
                int i = t + v * 1024;
                int l = i ^ j;
                if (l > i) {
                    float a_s = ss[i], b_s = ss[l];
                    int   a_i = si[i], b_i = si[l];
                    bool before = (a_s > b_s) || (a_s == b_s && a_i < b_i);
                    bool up = ((i & k) == 0);
                    if (up ? !before : before) {
                        ss[i] = b_s; ss[l] = a_s;
                        si[i] = b_i; si[l] = a_i;
                    }
                }
            }
            __syncthreads();
        }
    }

    // gather/recompute boxes for the selected set
#pragma unroll
    for (int v = 0; v < 2; ++v) {
        int p = t + v * 1024;
        float s = ss[p];
        if (s >= SCORE_THR) { sb[p] = decode_box(feats, anchors, si[p]); alive[p] = 1; }
        else                { alive[p] = 0; }
    }
    __syncthreads();

    // 10 greedy rounds
    for (int r = 0; r < 10; ++r) {
        int local = 0x7fffffff;
        if (alive[t + 1024]) local = t + 1024;
        if (alive[t])        local = t;
        red[t] = local;
        __syncthreads();
        for (int off = 512; off > 0; off >>= 1) {
            if (t < off) { int o = red[t + off]; if (o < red[t]) red[t] = o; }
            __syncthreads();
        }
        int pos = red[0];
        bool valid = (pos != 0x7fffffff);
        float4 ab = make_float4(0.f, 0.f, 0.f, 0.f);
        float  asc = 0.f;
        if (valid) { ab = sb[pos]; asc = ss[pos]; }

        if (t == 0) {
            float r5 = 0.f;
            if (valid) r5 = (float)cls[si[pos]];
            out[r * 6 + 0] = valid ? ab.x : 0.f;
            out[r * 6 + 1] = valid ? ab.y : 0.f;
            out[r * 6 + 2] = valid ? ab.z : 0.f;
            out[r * 6 + 3] = valid ? ab.w : 0.f;
            out[r * 6 + 4] = valid ? asc  : 0.f;
            out[r * 6 + 5] = r5;
        }

        if (valid) {
            float aarea = fmaxf(ab.z - ab.x, 0.f) * fmaxf(ab.w - ab.y, 0.f);
#pragma unroll
            for (int v = 0; v < 2; ++v) {
                int p = t + v * 1024;
                if (alive[p]) {
                    float4 cb = sb[p];
                    float iy1 = fmaxf(ab.x, cb.x);
                    float ix1 = fmaxf(ab.y, cb.y);
                    float iy2 = fminf(ab.z, cb.z);
                    float ix2 = fminf(ab.w, cb.w);
                    float inter = fmaxf(iy2 - iy1, 0.f) * fmaxf(ix2 - ix1, 0.f);
                    float carea = fmaxf(cb.z - cb.x, 0.f) * fmaxf(cb.w - cb.y, 0.f);
                    float iou = inter / (aarea + carea - inter + 1e-9f);
                    if (iou > 0.5f) alive[p] = 0;   // self included (iou ~ 1)
                }
            }
        }
        __syncthreads();
    }
}

extern "C" void kernel_launch(void* const* d_in, const int* in_sizes, int n_in,
                              void* d_out, int out_size, void* d_ws, size_t ws_size,
                              hipStream_t stream) {
    const float* feats   = (const float*)d_in[0];
    const float* anchors = (const float*)d_in[1];
    char* ws = (char*)d_ws;

    unsigned int* ctrl   = (unsigned int*)(ws + 0);
    unsigned int* hist   = (unsigned int*)(ws + 256);
    float*        lscore = (float*)(ws + 33280);
    int*          lidx   = (int*)(ws + 41472);
    float*        scores = (float*)(ws + 65536);
    int*          cls    = (int*)(ws + 65536 + (size_t)N_CAND * 4);
    float*        out    = (float*)d_out;

    // zero ctrl + histogram (re-zeroed every call; harness does not re-poison)
    hipMemsetAsync(ws, 0, 256 + NBINS * 4, stream);

    decode_kernel <<<N_CAND / 128, 128, 0, stream>>>(feats, scores, cls, hist);
    cutoff_kernel <<<1, 1024, 0, stream>>>(hist, ctrl);
    compact_kernel<<<N_CAND / 256, 256, 0, stream>>>(scores, ctrl, lscore, lidx);
    nms_kernel    <<<1, 1024, 0, stream>>>(lscore, lidx, ctrl, feats, anchors, cls, out);
}

// Round 4
// 121.604 us; speedup vs baseline: 1.8930x; 1.8930x over previous
//
#include <hip/hip_runtime.h>

#define N_CAND 462080   // 16*76*76*5
#define NBINS  8192
#define TARGET 1024u
#define SMAX   2048
#define SCORE_THR 0.02f
#define HPAD 16         // one histogram bin per 64B cache line

// ---------------- ws layout (bytes) ----------------
// ctrl   : 2 x u32            @ 0        ([0]=compact count, [1]=cutoff bin)
// hist   : 8192 x 16 x u32    @ 1024     (padded: bin b at hist[b*16]) end 525312
// lscore : 2048 x f32         @ 525312
// lidx   : 2048 x i32         @ 533504
// scores : N x f32            @ 541696   end 2390016
// cls    : N x u8             @ 2390016  end 2852096  (~2.85 MB total)

// ============ Kernel 1: decode (HBM-bound, LDS-staged, NO atomics) ============
__global__ __launch_bounds__(128) void decode_kernel(
    const float* __restrict__ feats,
    float* __restrict__ scores, unsigned char* __restrict__ cls)
{
    __shared__ __align__(16) float lds[128 * 85];   // 43520 B
    const int t = threadIdx.x;
    const long long base = (long long)blockIdx.x * 128;

    // coalesced staging: 128*85 floats = 2720 float4, base is 16B-aligned
    const float4* __restrict__ src = (const float4*)(feats + base * 85);
    float4* dst = (float4*)lds;
#pragma unroll
    for (int i = 0; i < 22; ++i) {
        int p = t + i * 128;
        if (p < 2720) dst[p] = src[p];
    }
    __syncthreads();

    const float* f = lds + t * 85;   // stride 85 (odd) -> conflict-free
    const int ci = (int)base + t;

    // class argmax over raw logits (== argmax of softmax, first-index ties)
    float m = f[5];
    int cbest = 0;
#pragma unroll
    for (int k = 1; k < 80; ++k) {
        float v = f[5 + k];
        if (v > m) { m = v; cbest = k; }
    }
    // softmax max-prob = 1 / sum(exp(l - m))
    float s0 = 0.f, s1 = 0.f, s2 = 0.f, s3 = 0.f;
#pragma unroll
    for (int k = 0; k < 80; k += 4) {
        s0 += __expf(f[5 + k] - m);
        s1 += __expf(f[6 + k] - m);
        s2 += __expf(f[7 + k] - m);
        s3 += __expf(f[8 + k] - m);
    }
    float ssum = (s0 + s1) + (s2 + s3);
    float conf = 1.0f / (1.0f + __expf(-f[4]));
    float score = conf * (1.0f / ssum);

    cls[ci] = (unsigned char)cbest;
    scores[ci] = (score >= SCORE_THR) ? score : -1.0f;
}

// ============ Kernel 2: histogram (LDS-private, padded flush) ============
__global__ __launch_bounds__(1024) void hist_kernel(
    const float* __restrict__ scores, unsigned int* __restrict__ hist)
{
    __shared__ unsigned int lh[NBINS];   // 32 KB
    const int t = threadIdx.x;
#pragma unroll
    for (int i = 0; i < 8; ++i) lh[t * 8 + i] = 0u;
    __syncthreads();

    for (int i = blockIdx.x * 1024 + t; i < N_CAND; i += 64 * 1024) {
        float s = scores[i];
        if (s >= SCORE_THR) {
            int bin = (int)(s * (float)NBINS);
            bin = bin > (NBINS - 1) ? (NBINS - 1) : bin;
            atomicAdd(&lh[bin], 1u);
        }
    }
    __syncthreads();
#pragma unroll
    for (int i = 0; i < 8; ++i) {
        unsigned v = lh[t * 8 + i];
        if (v) atomicAdd(&hist[(t * 8 + i) * HPAD], v);
    }
}

// ============ Kernel 3: find cutoff bin (1 block) ============
__global__ __launch_bounds__(1024) void cutoff_kernel(
    const unsigned int* __restrict__ hist, unsigned int* __restrict__ ctrl)
{
    __shared__ unsigned int lh[NBINS];
    __shared__ unsigned int psum[1024];
    const int t = threadIdx.x;
    unsigned s = 0;
#pragma unroll
    for (int i = 0; i < 8; ++i) {
        unsigned v = hist[(t * 8 + i) * HPAD];
        lh[t * 8 + i] = v;
        s += v;
    }
    psum[t] = s;
    __syncthreads();
    // inclusive suffix scan (Hillis-Steele)
    for (int off = 1; off < 1024; off <<= 1) {
        unsigned add = (t + off < 1024) ? psum[t + off] : 0u;
        __syncthreads();
        psum[t] += add;
        __syncthreads();
    }
    unsigned St = psum[t];
    unsigned Sn = (t < 1023) ? psum[t + 1] : 0u;
    // unique crossing thread finds b* = max{b : suffix(b) >= TARGET}
    if (St >= TARGET && Sn < TARGET) {
        unsigned run = Sn;
#pragma unroll
        for (int i = 7; i >= 0; --i) {
            run += lh[t * 8 + i];
            if (run >= TARGET) { ctrl[1] = (unsigned)(t * 8 + i); break; }
        }
    }
    // if total < TARGET, ctrl[1] stays 0 (memset) -> select all valid
}

// ============ Kernel 4: compact candidates >= cutoff ============
__global__ __launch_bounds__(256) void compact_kernel(
    const float* __restrict__ scores, unsigned int* __restrict__ ctrl,
    float* __restrict__ lscore, int* __restrict__ lidx)
{
    int i = blockIdx.x * 256 + threadIdx.x;
    float sw = scores[i];
    if (sw >= SCORE_THR) {
        int bin = (int)(sw * (float)NBINS);
        bin = bin > (NBINS - 1) ? (NBINS - 1) : bin;
        if (bin >= (int)ctrl[1]) {
            unsigned pos = atomicAdd(&ctrl[0], 1u);
            if (pos < SMAX) { lscore[pos] = sw; lidx[pos] = i; }
        }
    }
}

// box decode for one candidate (matches reference formulas, fp32)
__device__ inline float4 decode_box(const float* __restrict__ feats,
                                    const float* __restrict__ anchors, int ci)
{
    int a = ci % 5;
    int cell = ci / 5;
    int gx = cell % 76;
    int gy = (cell / 76) % 76;
    const float* f = feats + (long long)ci * 85;
    float bx = (1.0f / (1.0f + __expf(-f[0])) + (float)gx) / 76.0f;
    float by = (1.0f / (1.0f + __expf(-f[1])) + (float)gy) / 76.0f;
    float bw = __expf(f[2]) * anchors[2 * a]     / 76.0f;
    float bh = __expf(f[3]) * anchors[2 * a + 1] / 76.0f;
    return make_float4(by - bh * 0.5f, bx - bw * 0.5f,
                       by + bh * 0.5f, bx + bw * 0.5f);  // y1,x1,y2,x2
}

// ============ Kernel 5: sort + greedy NMS (1 block) ============
__global__ __launch_bounds__(1024) void nms_kernel(
    const float* __restrict__ lscore, const int* __restrict__ lidx,
    const unsigned int* __restrict__ ctrl,
    const float* __restrict__ feats, const float* __restrict__ anchors,
    const unsigned char* __restrict__ cls, float* __restrict__ out)
{
    __shared__ float  ss[SMAX];
    __shared__ int    si[SMAX];
    __shared__ float4 sb[SMAX];
    __shared__ unsigned char alive[SMAX];
    __shared__ int red[1024];
    const int t = threadIdx.x;

    unsigned cnt = ctrl[0];
    int n = (cnt < (unsigned)SMAX) ? (int)cnt : SMAX;

#pragma unroll
    for (int v = 0; v < 2; ++v) {
        int p = t + v * 1024;
        if (p < n) { ss[p] = lscore[p]; si[p] = lidx[p]; }
        else       { ss[p] = -2.0f;     si[p] = 0x7fffffff; }
    }
    __syncthreads();

    // bitonic sort, rank = (score desc, idx asc)
    for (int k = 2; k <= SMAX; k <<= 1) {
        for (int j = k >> 1; j > 0; j >>= 1) {
#pragma unroll
            for (int v = 0; v < 2; ++v) {
                int i = t + v * 1024;
                int l = i ^ j;
                if (l > i) {
                    float a_s = ss[i], b_s = ss[l];
                    int   a_i = si[i], b_i = si[l];
                    bool before = (a_s > b_s) || (a_s == b_s && a_i < b_i);
                    bool up = ((i & k) == 0);
                    if (up ? !before : before) {
                        ss[i] = b_s; ss[l] = a_s;
                        si[i] = b_i; si[l] = a_i;
                    }
                }
            }
            __syncthreads();
        }
    }

    // gather/recompute boxes for the selected set
#pragma unroll
    for (int v = 0; v < 2; ++v) {
        int p = t + v * 1024;
        float s = ss[p];
        if (s >= SCORE_THR) { sb[p] = decode_box(feats, anchors, si[p]); alive[p] = 1; }
        else                { alive[p] = 0; }
    }
    __syncthreads();

    // 10 greedy rounds
    for (int r = 0; r < 10; ++r) {
        int local = 0x7fffffff;
        if (alive[t + 1024]) local = t + 1024;
        if (alive[t])        local = t;
        red[t] = local;
        __syncthreads();
        for (int off = 512; off > 0; off >>= 1) {
            if (t < off) { int o = red[t + off]; if (o < red[t]) red[t] = o; }
            __syncthreads();
        }
        int pos = red[0];
        bool valid = (pos != 0x7fffffff);
        float4 ab = make_float4(0.f, 0.f, 0.f, 0.f);
        float  asc = 0.f;
        if (valid) { ab = sb[pos]; asc = ss[pos]; }

        if (t == 0) {
            float r5 = 0.f;
            if (valid) r5 = (float)cls[si[pos]];
            out[r * 6 + 0] = valid ? ab.x : 0.f;
            out[r * 6 + 1] = valid ? ab.y : 0.f;
            out[r * 6 + 2] = valid ? ab.z : 0.f;
            out[r * 6 + 3] = valid ? ab.w : 0.f;
            out[r * 6 + 4] = valid ? asc  : 0.f;
            out[r * 6 + 5] = r5;
        }

        if (valid) {
            float aarea = fmaxf(ab.z - ab.x, 0.f) * fmaxf(ab.w - ab.y, 0.f);
#pragma unroll
            for (int v = 0; v < 2; ++v) {
                int p = t + v * 1024;
                if (alive[p]) {
                    float4 cb = sb[p];
                    float iy1 = fmaxf(ab.x, cb.x);
                    float ix1 = fmaxf(ab.y, cb.y);
                    float iy2 = fminf(ab.z, cb.z);
                    float ix2 = fminf(ab.w, cb.w);
                    float inter = fmaxf(iy2 - iy1, 0.f) * fmaxf(ix2 - ix1, 0.f);
                    float carea = fmaxf(cb.z - cb.x, 0.f) * fmaxf(cb.w - cb.y, 0.f);
                    float iou = inter / (aarea + carea - inter + 1e-9f);
                    if (iou > 0.5f) alive[p] = 0;   // self included (iou ~ 1)
                }
            }
        }
        __syncthreads();
    }
}

extern "C" void kernel_launch(void* const* d_in, const int* in_sizes, int n_in,
                              void* d_out, int out_size, void* d_ws, size_t ws_size,
                              hipStream_t stream) {
    const float* feats   = (const float*)d_in[0];
    const float* anchors = (const float*)d_in[1];
    char* ws = (char*)d_ws;

    unsigned int*  ctrl   = (unsigned int*)(ws + 0);
    unsigned int*  hist   = (unsigned int*)(ws + 1024);
    float*         lscore = (float*)(ws + 525312);
    int*           lidx   = (int*)(ws + 533504);
    float*         scores = (float*)(ws + 541696);
    unsigned char* cls    = (unsigned char*)(ws + 2390016);
    float*         out    = (float*)d_out;

    // zero ctrl + padded histogram (re-zeroed every call)
    hipMemsetAsync(ws, 0, 1024 + NBINS * HPAD * 4, stream);

    decode_kernel <<<N_CAND / 128, 128, 0, stream>>>(feats, scores, cls);
    hist_kernel   <<<64, 1024, 0, stream>>>(scores, hist);
    cutoff_kernel <<<1, 1024, 0, stream>>>(hist, ctrl);
    compact_kernel<<<N_CAND / 256, 256, 0, stream>>>(scores, ctrl, lscore, lidx);
    nms_kernel    <<<1, 1024, 0, stream>>>(lscore, lidx, ctrl, feats, anchors, cls, out);
}

// Round 5
// 76.476 us; speedup vs baseline: 3.0101x; 1.5901x over previous
//
#include <hip/hip_runtime.h>
#include <stdint.h>

#define N_CAND 462080   // 16*76*76*5
#define NBINS  8192
#define HIST_BLOCKS 64
#define TARGET 256u
#define SMAX   1024
#define SCORE_THR 0.02f

// ---------------- ws layout (bytes) ----------------
// ctrl      : 2 x u32        @ 0        ([0]=compact count, [1]=cutoff bin)
// hist_part : 64 x 8192 u16  @ 256      end 1048832   (written unconditionally)
// lscore    : 1024 x f32     @ 1048832  end 1052928
// lidx      : 1024 x i32     @ 1052928  end 1057024
// scores    : N x f32        @ 1057024  end 2905344
// cls       : N x u8         @ 2905344  end 3367424   (~3.4 MB total)
// NO memset needed: every word read was written this call, in dispatch order.

typedef const __attribute__((address_space(1))) uint32_t* gas1_u32;
typedef __attribute__((address_space(3))) uint32_t*       las3_u32;
#define GLOAD_LDS16(g, l) __builtin_amdgcn_global_load_lds( \
    (gas1_u32)(const void*)(g), (las3_u32)(void*)(l), 16, 0, 0)

// ============ Kernel 1: decode (HBM-bound, async LDS staging, no atomics) ============
__global__ __launch_bounds__(128) void decode_kernel(
    const float* __restrict__ feats,
    float* __restrict__ scores, unsigned char* __restrict__ cls)
{
    __shared__ __align__(16) float lds[128 * 85];   // 43520 B
    const int t = threadIdx.x;
    const long long base = (long long)blockIdx.x * 128;

    // 2720 float4 per block; p = i*128 + wave*64 + lane -> lane-linear LDS dest
    const float4* __restrict__ src = (const float4*)(feats + base * 85);
    float4* dst = (float4*)lds;
#pragma unroll
    for (int i = 0; i < 22; ++i) {
        int p = t + i * 128;
        if (p < 2720) GLOAD_LDS16(src + p, dst + p);
    }
    __syncthreads();   // compiler drains vmcnt before barrier -> LDS valid

    const float* f = lds + t * 85;   // stride 85: lanes t,t+32 share bank = free 2-way
    const int ci = (int)base + t;

    // class argmax over raw logits (== argmax of softmax, first-index ties)
    float m = f[5];
    int cbest = 0;
#pragma unroll
    for (int k = 1; k < 80; ++k) {
        float v = f[5 + k];
        if (v > m) { m = v; cbest = k; }
    }
    // softmax max-prob = 1 / sum(exp(l - m))
    float s0 = 0.f, s1 = 0.f, s2 = 0.f, s3 = 0.f;
#pragma unroll
    for (int k = 0; k < 80; k += 4) {
        s0 += __expf(f[5 + k] - m);
        s1 += __expf(f[6 + k] - m);
        s2 += __expf(f[7 + k] - m);
        s3 += __expf(f[8 + k] - m);
    }
    float ssum = (s0 + s1) + (s2 + s3);
    float conf = 1.0f / (1.0f + __expf(-f[4]));
    float score = conf * (1.0f / ssum);

    cls[ci] = (unsigned char)cbest;
    scores[ci] = (score >= SCORE_THR) ? score : -1.0f;
}

// ============ Kernel 2: histogram (LDS-private, unconditional u16 flush, NO global atomics) ============
__global__ __launch_bounds__(1024) void hist_kernel(
    const float* __restrict__ scores, unsigned short* __restrict__ hist_part)
{
    __shared__ unsigned int lh[NBINS];   // 32 KB
    const int t = threadIdx.x;
#pragma unroll
    for (int i = 0; i < 8; ++i) lh[t * 8 + i] = 0u;
    __syncthreads();

    for (int i = blockIdx.x * 1024 + t; i < N_CAND; i += HIST_BLOCKS * 1024) {
        float s = scores[i];
        if (s >= SCORE_THR) {
            int bin = (int)(s * (float)NBINS);
            bin = bin > (NBINS - 1) ? (NBINS - 1) : bin;
            atomicAdd(&lh[bin], 1u);   // LDS atomic only
        }
    }
    __syncthreads();
    unsigned short* outp = hist_part + (size_t)blockIdx.x * NBINS;
#pragma unroll
    for (int i = 0; i < 8; ++i)
        outp[t * 8 + i] = (unsigned short)lh[t * 8 + i];   // per-block count <= 7220 < 65536
}

// ============ Kernel 3: sum parts + suffix scan -> cutoff bin (1 block) ============
__global__ __launch_bounds__(1024) void cutoff_kernel(
    const unsigned short* __restrict__ hist_part, unsigned int* __restrict__ ctrl)
{
    __shared__ unsigned int lh[NBINS];          // 32 KB
    __shared__ unsigned int pa[1024], pb[1024]; // 8 KB ping-pong
    const int t = threadIdx.x;

    unsigned bsum[8];
#pragma unroll
    for (int i = 0; i < 8; ++i) bsum[i] = 0u;
    for (int p = 0; p < HIST_BLOCKS; ++p) {
        const unsigned short* hp = hist_part + (size_t)p * NBINS + t * 8;
#pragma unroll
        for (int i = 0; i < 8; ++i) bsum[i] += hp[i];   // 16 B/lane, coalesced
    }
    unsigned s = 0;
#pragma unroll
    for (int i = 0; i < 8; ++i) { lh[t * 8 + i] = bsum[i]; s += bsum[i]; }
    pa[t] = s;
    __syncthreads();

    // inclusive suffix scan, ping-pong (10 barriers)
    unsigned int* srcb = pa; unsigned int* dstb = pb;
    for (int off = 1; off < 1024; off <<= 1) {
        unsigned v = srcb[t] + ((t + off < 1024) ? srcb[t + off] : 0u);
        dstb[t] = v;
        __syncthreads();
        unsigned int* tmp = srcb; srcb = dstb; dstb = tmp;
    }
    unsigned St = srcb[t];
    unsigned Sn = (t < 1023) ? srcb[t + 1] : 0u;

    if (t == 0) {
        ctrl[0] = 0u;                       // reset compact counter (runs before compact)
        if (St < TARGET) ctrl[1] = 0u;      // total < TARGET -> keep all valid
    }
    // unique crossing thread finds b* = max{b : suffix(b) >= TARGET}
    if (St >= TARGET && Sn < TARGET) {
        unsigned run = Sn;
#pragma unroll
        for (int i = 7; i >= 0; --i) {
            run += lh[t * 8 + i];
            if (run >= TARGET) { ctrl[1] = (unsigned)(t * 8 + i); break; }
        }
    }
}

// ============ Kernel 4: compact candidates with bin >= cutoff ============
__global__ __launch_bounds__(256) void compact_kernel(
    const float* __restrict__ scores, unsigned int* __restrict__ ctrl,
    float* __restrict__ lscore, int* __restrict__ lidx)
{
    int i = blockIdx.x * 256 + threadIdx.x;
    float sw = scores[i];
    if (sw >= SCORE_THR) {
        int bin = (int)(sw * (float)NBINS);
        bin = bin > (NBINS - 1) ? (NBINS - 1) : bin;
        if (bin >= (int)ctrl[1]) {
            unsigned pos = atomicAdd(&ctrl[0], 1u);
            if (pos < SMAX) { lscore[pos] = sw; lidx[pos] = i; }
        }
    }
}

// box decode for one candidate (matches reference formulas, fp32)
__device__ inline float4 decode_box(const float* __restrict__ feats,
                                    const float* __restrict__ anchors, int ci)
{
    int a = ci % 5;
    int cell = ci / 5;
    int gx = cell % 76;
    int gy = (cell / 76) % 76;
    const float* f = feats + (long long)ci * 85;
    float bx = (1.0f / (1.0f + __expf(-f[0])) + (float)gx) / 76.0f;
    float by = (1.0f / (1.0f + __expf(-f[1])) + (float)gy) / 76.0f;
    float bw = __expf(f[2]) * anchors[2 * a]     / 76.0f;
    float bh = __expf(f[3]) * anchors[2 * a + 1] / 76.0f;
    return make_float4(by - bh * 0.5f, bx - bw * 0.5f,
                       by + bh * 0.5f, bx + bw * 0.5f);  // y1,x1,y2,x2
}

// ============ Kernel 5: bitonic sort + greedy NMS (1 block, 1 elem/thread) ============
__global__ __launch_bounds__(1024) void nms_kernel(
    const float* __restrict__ lscore, const int* __restrict__ lidx,
    const unsigned int* __restrict__ ctrl,
    const float* __restrict__ feats, const float* __restrict__ anchors,
    const unsigned char* __restrict__ cls, float* __restrict__ out)
{
    __shared__ float  ss[SMAX];
    __shared__ int    si[SMAX];
    __shared__ float4 sb[SMAX];
    __shared__ int    wred[16];
    __shared__ int    posb;
    const int t = threadIdx.x;

    unsigned cnt = ctrl[0];
    int n = (cnt < (unsigned)SMAX) ? (int)cnt : SMAX;

    if (t < n) { ss[t] = lscore[t]; si[t] = lidx[t]; }
    else       { ss[t] = -2.0f;     si[t] = 0x7fffffff; }
    __syncthreads();

    // bitonic sort, rank = (score desc, idx asc): 55 rounds
    for (int k = 2; k <= SMAX; k <<= 1) {
        for (int j = k >> 1; j > 0; j >>= 1) {
            int l = t ^ j;
            if (l > t) {
                float a_s = ss[t], b_s = ss[l];
                int   a_i = si[t], b_i = si[l];
                bool before = (a_s > b_s) || (a_s == b_s && a_i < b_i);
                bool up = ((t & k) == 0);
                if (up ? !before : before) {
                    ss[t] = b_s; ss[l] = a_s;
                    si[t] = b_i; si[l] = a_i;
                }
            }
            __syncthreads();
        }
    }

    // per-thread element (t = sorted rank)
    float msc  = ss[t];
    int   midx = si[t];
    bool  aliveb = (msc >= SCORE_THR);
    float4 mb = make_float4(0.f, 0.f, 0.f, 0.f);
    float mcls = 0.f;
    if (aliveb) { mb = decode_box(feats, anchors, midx); mcls = (float)cls[midx]; }
    sb[t] = mb;
    __syncthreads();

    // 10 greedy rounds, 2 barriers each
    for (int r = 0; r < 10; ++r) {
        int val = aliveb ? t : 0x7fffffff;
#pragma unroll
        for (int msk = 32; msk > 0; msk >>= 1) {
            int o = __shfl_xor(val, msk);
            val = o < val ? o : val;
        }
        if ((t & 63) == 0) wred[t >> 6] = val;
        __syncthreads();
        if (t < 64) {
            int v = (t < 16) ? wred[t] : 0x7fffffff;
#pragma unroll
            for (int msk = 8; msk > 0; msk >>= 1) {
                int o = __shfl_xor(v, msk);
                v = o < v ? o : v;
            }
            if (t == 0) posb = v;
        }
        __syncthreads();
        int pos = posb;

        if (pos == 0x7fffffff) {
            if (t == 0) {
#pragma unroll
                for (int q = 0; q < 6; ++q) out[r * 6 + q] = 0.f;
            }
        } else {
            if (t == pos) {
                out[r * 6 + 0] = mb.x;
                out[r * 6 + 1] = mb.y;
                out[r * 6 + 2] = mb.z;
                out[r * 6 + 3] = mb.w;
                out[r * 6 + 4] = msc;
                out[r * 6 + 5] = mcls;
            }
            float4 ab = sb[pos];   // broadcast read
            if (aliveb) {
                float aarea = fmaxf(ab.z - ab.x, 0.f) * fmaxf(ab.w - ab.y, 0.f);
                float iy1 = fmaxf(ab.x, mb.x);
                float ix1 = fmaxf(ab.y, mb.y);
                float iy2 = fminf(ab.z, mb.z);
                float ix2 = fminf(ab.w, mb.w);
                float inter = fmaxf(iy2 - iy1, 0.f) * fmaxf(ix2 - ix1, 0.f);
                float carea = fmaxf(mb.z - mb.x, 0.f) * fmaxf(mb.w - mb.y, 0.f);
                float iou = inter / (aarea + carea - inter + 1e-9f);
                if (iou > 0.5f) aliveb = false;
            }
            if (t == pos) aliveb = false;   // reference also kills idx==idx (zero-area safety)
        }
    }
}

extern "C" void kernel_launch(void* const* d_in, const int* in_sizes, int n_in,
                              void* d_out, int out_size, void* d_ws, size_t ws_size,
                              hipStream_t stream) {
    const float* feats   = (const float*)d_in[0];
    const float* anchors = (const float*)d_in[1];
    char* ws = (char*)d_ws;

    unsigned int*   ctrl      = (unsigned int*)(ws + 0);
    unsigned short* hist_part = (unsigned short*)(ws + 256);
    float*          lscore    = (float*)(ws + 1048832);
    int*            lidx      = (int*)(ws + 1052928);
    float*          scores    = (float*)(ws + 1057024);
    unsigned char*  cls       = (unsigned char*)(ws + 2905344);
    float*          out       = (float*)d_out;

    decode_kernel <<<N_CAND / 128, 128, 0, stream>>>(feats, scores, cls);
    hist_kernel   <<<HIST_BLOCKS, 1024, 0, stream>>>(scores, hist_part);
    cutoff_kernel <<<1, 1024, 0, stream>>>(hist_part, ctrl);
    compact_kernel<<<N_CAND / 256, 256, 0, stream>>>(scores, ctrl, lscore, lidx);
    nms_kernel    <<<1, 1024, 0, stream>>>(lscore, lidx, ctrl, feats, anchors, cls, out);
}

// Round 7
// 65.253 us; speedup vs baseline: 3.5277x; 1.1720x over previous
//
#include <hip/hip_runtime.h>
#include <stdint.h>

#define N_CAND 462080   // 16*76*76*5
#define NBINS  8192
#define HIST_BLOCKS 64
#define TARGET 256u
#define SMAX   1024
#define SCORE_THR 0.02f

// ---------------- ws layout (bytes) ----------------
// ctrl      : 2 x u32        @ 0        ([0]=compact count, [1]=cutoff bin)
// hist_part : 64 x 8192 u16  @ 256      end 1048832   (written unconditionally)
// lscore    : 1024 x f32     @ 1048832  end 1052928
// lidx      : 1024 x i32     @ 1052928  end 1057024
// scores    : N x f32        @ 1057024  end 2905344
// cls       : N x u8         @ 2905344  end 3367424   (~3.4 MB total)
// NO memset needed: every word read was written this call, in dispatch order.

typedef const __attribute__((address_space(1))) uint32_t* gas1_u32;
typedef __attribute__((address_space(3))) uint32_t*       las3_u32;
#define GLOAD_LDS16(g, l) __builtin_amdgcn_global_load_lds( \
    (gas1_u32)(const void*)(g), (las3_u32)(void*)(l), 16, 0, 0)

// ============ Kernel 1: decode — one wave per block, no barriers ============
// 64 candidates/block, per-wave async LDS staging + per-wave vmcnt wait.
// 21760 B LDS -> 7 blocks/CU; waves cycle load/compute independently so
// some wave is always loading -> HBM stays saturated.
__global__ __launch_bounds__(64) void decode_kernel(
    const float* __restrict__ feats,
    float* __restrict__ scores, unsigned char* __restrict__ cls)
{
    __shared__ __align__(16) float lds[64 * 85];   // 21760 B
    const int t = threadIdx.x;                     // 0..63 (one wave)
    const long long base = (long long)blockIdx.x * 64;

    // 64*85 floats = 1360 float4; 21 full rounds + 16-lane tail.
    // LDS dest pattern = uniform base + lane*16 (HW-required, m104/m108).
    const float4* __restrict__ src = (const float4*)(feats + base * 85);
    float4* dst = (float4*)lds;
#pragma unroll
    for (int i = 0; i < 21; ++i)
        GLOAD_LDS16(src + i * 64 + t, dst + i * 64 + t);
    if (t < 16) GLOAD_LDS16(src + 21 * 64 + t, dst + 21 * 64 + t);

    asm volatile("s_waitcnt vmcnt(0)" ::: "memory");   // per-wave drain, no barrier
    __builtin_amdgcn_sched_barrier(0);

    const float* f = lds + t * 85;   // bank (l*21+k)%32: permutation -> conflict-free
    const int ci = (int)base + t;

    // class argmax over raw logits (== argmax of softmax, first-index ties)
    float m = f[5];
    int cbest = 0;
#pragma unroll
    for (int k = 1; k < 80; ++k) {
        float v = f[5 + k];
        if (v > m) { m = v; cbest = k; }
    }
    // softmax max-prob = 1 / sum(exp(l - m))
    float s0 = 0.f, s1 = 0.f, s2 = 0.f, s3 = 0.f;
#pragma unroll
    for (int k = 0; k < 80; k += 4) {
        s0 += __expf(f[5 + k] - m);
        s1 += __expf(f[6 + k] - m);
        s2 += __expf(f[7 + k] - m);
        s3 += __expf(f[8 + k] - m);
    }
    float ssum = (s0 + s1) + (s2 + s3);
    float conf = 1.0f / (1.0f + __expf(-f[4]));
    float score = conf * (1.0f / ssum);

    cls[ci] = (unsigned char)cbest;
    scores[ci] = (score >= SCORE_THR) ? score : -1.0f;
}

// ============ Kernel 2: histogram (LDS-private, unconditional u16 flush, NO global atomics) ============
__global__ __launch_bounds__(1024) void hist_kernel(
    const float* __restrict__ scores, unsigned short* __restrict__ hist_part)
{
    __shared__ unsigned int lh[NBINS];   // 32 KB
    const int t = threadIdx.x;
#pragma unroll
    for (int i = 0; i < 8; ++i) lh[t * 8 + i] = 0u;
    __syncthreads();

    for (int i = blockIdx.x * 1024 + t; i < N_CAND; i += HIST_BLOCKS * 1024) {
        float s = scores[i];
        if (s >= SCORE_THR) {
            int bin = (int)(s * (float)NBINS);
            bin = bin > (NBINS - 1) ? (NBINS - 1) : bin;
            atomicAdd(&lh[bin], 1u);   // LDS atomic only
        }
    }
    __syncthreads();
    unsigned short* outp = hist_part + (size_t)blockIdx.x * NBINS;
#pragma unroll
    for (int i = 0; i < 8; ++i)
        outp[t * 8 + i] = (unsigned short)lh[t * 8 + i];   // per-block count <= 7220 < 65536
}

// ============ Kernel 3: sum parts + suffix scan -> cutoff bin (1 block) ============
__global__ __launch_bounds__(1024) void cutoff_kernel(
    const unsigned short* __restrict__ hist_part, unsigned int* __restrict__ ctrl)
{
    __shared__ unsigned int lh[NBINS];          // 32 KB
    __shared__ unsigned int pa[1024], pb[1024]; // 8 KB ping-pong
    const int t = threadIdx.x;

    unsigned bsum[8];
#pragma unroll
    for (int i = 0; i < 8; ++i) bsum[i] = 0u;
    for (int p = 0; p < HIST_BLOCKS; ++p) {
        const unsigned short* hp = hist_part + (size_t)p * NBINS + t * 8;
#pragma unroll
        for (int i = 0; i < 8; ++i) bsum[i] += hp[i];   // 16 B/lane, coalesced
    }
    unsigned s = 0;
#pragma unroll
    for (int i = 0; i < 8; ++i) { lh[t * 8 + i] = bsum[i]; s += bsum[i]; }
    pa[t] = s;
    __syncthreads();

    // inclusive suffix scan, ping-pong (10 barriers)
    unsigned int* srcb = pa; unsigned int* dstb = pb;
    for (int off = 1; off < 1024; off <<= 1) {
        unsigned v = srcb[t] + ((t + off < 1024) ? srcb[t + off] : 0u);
        dstb[t] = v;
        __syncthreads();
        unsigned int* tmp = srcb; srcb = dstb; dstb = tmp;
    }
    unsigned St = srcb[t];
    unsigned Sn = (t < 1023) ? srcb[t + 1] : 0u;

    if (t == 0) {
        ctrl[0] = 0u;                       // reset compact counter (runs before compact)
        if (St < TARGET) ctrl[1] = 0u;      // total < TARGET -> keep all valid
    }
    // unique crossing thread finds b* = max{b : suffix(b) >= TARGET}
    if (St >= TARGET && Sn < TARGET) {
        unsigned run = Sn;
#pragma unroll
        for (int i = 7; i >= 0; --i) {
            run += lh[t * 8 + i];
            if (run >= TARGET) { ctrl[1] = (unsigned)(t * 8 + i); break; }
        }
    }
}

// ============ Kernel 4: compact candidates with bin >= cutoff ============
__global__ __launch_bounds__(256) void compact_kernel(
    const float* __restrict__ scores, unsigned int* __restrict__ ctrl,
    float* __restrict__ lscore, int* __restrict__ lidx)
{
    int i = blockIdx.x * 256 + threadIdx.x;
    float sw = scores[i];
    if (sw >= SCORE_THR) {
        int bin = (int)(sw * (float)NBINS);
        bin = bin > (NBINS - 1) ? (NBINS - 1) : bin;
        if (bin >= (int)ctrl[1]) {
            unsigned pos = atomicAdd(&ctrl[0], 1u);
            if (pos < SMAX) { lscore[pos] = sw; lidx[pos] = i; }
        }
    }
}

// box decode for one candidate (matches reference formulas, fp32)
__device__ inline float4 decode_box(const float* __restrict__ feats,
                                    const float* __restrict__ anchors, int ci)
{
    int a = ci % 5;
    int cell = ci / 5;
    int gx = cell % 76;
    int gy = (cell / 76) % 76;
    const float* f = feats + (long long)ci * 85;
    float bx = (1.0f / (1.0f + __expf(-f[0])) + (float)gx) / 76.0f;
    float by = (1.0f / (1.0f + __expf(-f[1])) + (float)gy) / 76.0f;
    float bw = __expf(f[2]) * anchors[2 * a]     / 76.0f;
    float bh = __expf(f[3]) * anchors[2 * a + 1] / 76.0f;
    return make_float4(by - bh * 0.5f, bx - bw * 0.5f,
                       by + bh * 0.5f, bx + bw * 0.5f);  // y1,x1,y2,x2
}

// ============ Kernel 5: sort-free greedy NMS (1 block, 10 argmax rounds) ============
// Greedy NMS only needs the max-score alive element per round, not a sort.
// Key = (score_bits << 32) | (0xFFFFFFFF - idx): max key == max score,
// tie -> min idx (reference argmax tie-break). Dead/padding key = 0.
__global__ __launch_bounds__(1024) void nms_kernel(
    const float* __restrict__ lscore, const int* __restrict__ lidx,
    const unsigned int* __restrict__ ctrl,
    const float* __restrict__ feats, const float* __restrict__ anchors,
    const unsigned char* __restrict__ cls, float* __restrict__ out)
{
    __shared__ unsigned long long wkey[16];
    __shared__ unsigned long long bkey;
    __shared__ float4 bbox;
    const int t = threadIdx.x;

    unsigned cnt = ctrl[0];
    int n = (cnt < (unsigned)SMAX) ? (int)cnt : SMAX;

    unsigned long long key = 0ull;
    float4 mb = make_float4(0.f, 0.f, 0.f, 0.f);
    float  msc = 0.f, mcls = 0.f;
    unsigned midx = 0xFFFFFFFFu;
    bool aliveb = false;
    if (t < n) {
        msc  = lscore[t];
        midx = (unsigned)lidx[t];
        key  = ((unsigned long long)__float_as_uint(msc) << 32)
             | (unsigned long long)(0xFFFFFFFFu - midx);
        mb   = decode_box(feats, anchors, (int)midx);
        mcls = (float)cls[midx];
        aliveb = true;
    }

    for (int r = 0; r < 10; ++r) {
        // block argmax of key
        unsigned long long k0 = aliveb ? key : 0ull;
#pragma unroll
        for (int msk = 32; msk > 0; msk >>= 1) {
            unsigned long long o = __shfl_xor(k0, msk);
            k0 = (o > k0) ? o : k0;
        }
        if ((t & 63) == 0) wkey[t >> 6] = k0;
        __syncthreads();
        if (t < 16) {
            unsigned long long v = wkey[t];
#pragma unroll
            for (int msk = 8; msk > 0; msk >>= 1) {
                unsigned long long o = __shfl_xor(v, msk);
                v = (o > v) ? o : v;
            }
            if (t == 0) bkey = v;
        }
        __syncthreads();

        unsigned long long wk = bkey;
        bool have = (wk != 0ull);
        unsigned widx = 0xFFFFFFFFu;
        if (have) widx = 0xFFFFFFFFu - (unsigned)(wk & 0xFFFFFFFFull);

        if (have && aliveb && midx == widx) {   // unique winner thread
            bbox = mb;
            out[r * 6 + 0] = mb.x;
            out[r * 6 + 1] = mb.y;
            out[r * 6 + 2] = mb.z;
            out[r * 6 + 3] = mb.w;
            out[r * 6 + 4] = msc;
            out[r * 6 + 5] = mcls;
            aliveb = false;                     // self-suppress (zero-area safety)
        }
        if (!have && t == 0) {
#pragma unroll
            for (int q = 0; q < 6; ++q) out[r * 6 + q] = 0.f;
        }
        __syncthreads();                        // bbox visible to all

        if (have && aliveb) {
            float4 ab = bbox;
            float aarea = fmaxf(ab.z - ab.x, 0.f) * fmaxf(ab.w - ab.y, 0.f);
            float iy1 = fmaxf(ab.x, mb.x);
            float ix1 = fmaxf(ab.y, mb.y);
            float iy2 = fminf(ab.z, mb.z);
            float ix2 = fminf(ab.w, mb.w);
            float inter = fmaxf(iy2 - iy1, 0.f) * fmaxf(ix2 - ix1, 0.f);
            float carea = fmaxf(mb.z - mb.x, 0.f) * fmaxf(mb.w - mb.y, 0.f);
            float iou = inter / (aarea + carea - inter + 1e-9f);
            if (iou > 0.5f) aliveb = false;
        }
        // next round's wkey/bkey writes are fenced by the two barriers above
    }
}

extern "C" void kernel_launch(void* const* d_in, const int* in_sizes, int n_in,
                              void* d_out, int out_size, void* d_ws, size_t ws_size,
                              hipStream_t stream) {
    const float* feats   = (const float*)d_in[0];
    const float* anchors = (const float*)d_in[1];
    char* ws = (char*)d_ws;

    unsigned int*   ctrl      = (unsigned int*)(ws + 0);
    unsigned short* hist_part = (unsigned short*)(ws + 256);
    float*          lscore    = (float*)(ws + 1048832);
    int*            lidx      = (int*)(ws + 1052928);
    float*          scores    = (float*)(ws + 1057024);
    unsigned char*  cls       = (unsigned char*)(ws + 2905344);
    float*          out       = (float*)d_out;

    decode_kernel <<<N_CAND / 64, 64, 0, stream>>>(feats, scores, cls);
    hist_kernel   <<<HIST_BLOCKS, 1024, 0, stream>>>(scores, hist_part);
    cutoff_kernel <<<1, 1024, 0, stream>>>(hist_part, ctrl);
    compact_kernel<<<N_CAND / 256, 256, 0, stream>>>(scores, ctrl, lscore, lidx);
    nms_kernel    <<<1, 1024, 0, stream>>>(lscore, lidx, ctrl, feats, anchors, cls, out);
}